// Round 1
// baseline (51.760 us; speedup 1.0000x reference)
//
#include <hip/hip_runtime.h>
#include <hip/hip_bf16.h>

// ThreeWayAttention: B=32, S=128, D=32, F=32, U=11
// scores separable: p_ijk ∝ E_A[i,j] E_B[j,k] E_C[i,k], E_X = exp(X/9), diag=0.

#define B_ 32
#define S_ 128
#define D_ 32
#define F_ 32
#define U_ 11

// ---------------- Kernel 1: Q projections + E matrices ----------------
// grid: B*3 blocks, 256 threads. block (b, m): m=0 -> E_A=exp(Q1.Q2^T/9),
// m=1 -> E_B=exp(Q2.Q3^T/9), m=2 -> E_C=exp(Q1.Q3^T/9); diagonal -> 0.
__global__ void k_qe(const float* __restrict__ X,
                     const float* __restrict__ W1, const float* __restrict__ b1,
                     const float* __restrict__ W2, const float* __restrict__ b2,
                     const float* __restrict__ W3, const float* __restrict__ b3,
                     float* __restrict__ E) {
    int blk = blockIdx.x;
    int b = blk / 3, m = blk % 3;
    __shared__ float Xs[S_][33];
    __shared__ float QL[S_][13];
    __shared__ float QR[S_][13];
    __shared__ float Ws[2][D_][U_];
    __shared__ float bs[2][U_];
    int t = threadIdx.x;

    const float* Xb = X + (size_t)b * S_ * D_;
    for (int idx = t; idx < S_ * D_; idx += 256) {
        int r = idx >> 5, d = idx & 31;
        Xs[r][d] = Xb[idx];
    }
    const float* WL = (m == 0) ? W1 : (m == 1) ? W2 : W1;
    const float* WR = (m == 0) ? W2 : (m == 1) ? W3 : W3;
    const float* bL = (m == 0) ? b1 : (m == 1) ? b2 : b1;
    const float* bR = (m == 0) ? b2 : (m == 1) ? b3 : b3;
    for (int idx = t; idx < D_ * U_; idx += 256) {
        Ws[0][idx / U_][idx % U_] = WL[idx];
        Ws[1][idx / U_][idx % U_] = WR[idx];
    }
    if (t < U_) { bs[0][t] = bL[t]; bs[1][t] = bR[t]; }
    __syncthreads();

    {   // threads 0..127 compute QL rows, 128..255 compute QR rows
        int side = t >> 7;
        int r = t & 127;
        float q[U_];
#pragma unroll
        for (int u = 0; u < U_; ++u) q[u] = bs[side][u];
#pragma unroll
        for (int d = 0; d < D_; ++d) {
            float x = Xs[r][d];
#pragma unroll
            for (int u = 0; u < U_; ++u) q[u] += x * Ws[side][d][u];
        }
        float* dst = side ? &QR[r][0] : &QL[r][0];
#pragma unroll
        for (int u = 0; u < U_; ++u) dst[u] = q[u];
    }
    __syncthreads();

    float* Eb = E + ((size_t)b * 3 + m) * (S_ * S_);
    const float inv9 = 1.0f / 9.0f;
    for (int idx = t; idx < S_ * S_; idx += 256) {
        int i = idx >> 7, j = idx & 127;
        float s = 0.f;
#pragma unroll
        for (int u = 0; u < U_; ++u) s += QL[i][u] * QR[j][u];
        Eb[idx] = (i == j) ? 0.f : __expf(s * inv9);
    }
}

// ---------------- Kernel 2: contractions + marginals ----------------
// grid: B*4 blocks (b, job, half), 256 threads, 8x4 register tile each.
// job 0: G[i,j]=sum_k EC[i,k]EB[j,k]; v=EA[i,j]*G -> m1 (partial over j-half),
//        m2 (complete). job 1: H[i,k]=sum_j EA[i,j]EB[j,k]; v=EC[i,k]*H -> m3.
__global__ void k_gemm(const float* __restrict__ E,
                       float* __restrict__ m1p,   // [B][2][128]
                       float* __restrict__ m2,    // [B][128]
                       float* __restrict__ m3) {  // [B][128]
    int blk = blockIdx.x;
    int b = blk >> 2, sub = blk & 3, job = sub >> 1, h = sub & 1;
    const float* EA = E + (size_t)b * 3 * S_ * S_;
    const float* EB = EA + S_ * S_;
    const float* EC = EB + S_ * S_;
    const float* P  = job ? EA : EC;  // [i][contract]
    const float* Wt = job ? EC : EA;  // combine weight [i][col]

    __shared__ float Ps[S_][33];
    __shared__ float Bs[64][33];
    __shared__ float red1[S_][17];
    __shared__ float red2[64][17];

    int t = threadIdx.x;
    int tx = t & 15, ty = t >> 4;

    float acc[8][4] = {};
    for (int t0 = 0; t0 < S_; t0 += 32) {
        __syncthreads();
        for (int idx = t; idx < S_ * 32; idx += 256) {
            int i = idx >> 5, tt = idx & 31;
            Ps[i][tt] = P[i * S_ + t0 + tt];
        }
        if (job == 0) {
            for (int idx = t; idx < 64 * 32; idx += 256) {
                int jl = idx >> 5, tt = idx & 31;
                Bs[jl][tt] = EB[(h * 64 + jl) * S_ + t0 + tt];
            }
        } else {
            for (int idx = t; idx < 32 * 64; idx += 256) {
                int jj = idx >> 6, kl = idx & 63;
                Bs[kl][jj] = EB[(t0 + jj) * S_ + h * 64 + kl];
            }
        }
        __syncthreads();
#pragma unroll
        for (int tt = 0; tt < 32; ++tt) {
            float a[8], bb[4];
#pragma unroll
            for (int r = 0; r < 8; ++r) a[r] = Ps[ty * 8 + r][tt];
#pragma unroll
            for (int c = 0; c < 4; ++c) bb[c] = Bs[tx * 4 + c][tt];
#pragma unroll
            for (int r = 0; r < 8; ++r)
#pragma unroll
                for (int c = 0; c < 4; ++c) acc[r][c] += a[r] * bb[c];
        }
    }

    // combine with elementwise weight, accumulate row/col sums
    float rsum[8] = {}, csum[4] = {};
#pragma unroll
    for (int r = 0; r < 8; ++r) {
        int i = ty * 8 + r;
        const float4* wp = (const float4*)&Wt[i * S_ + h * 64 + tx * 4];
        float4 w = wp[0];
        float v0 = w.x * acc[r][0];
        float v1 = w.y * acc[r][1];
        float v2 = w.z * acc[r][2];
        float v3 = w.w * acc[r][3];
        rsum[r] += v0 + v1 + v2 + v3;
        csum[0] += v0; csum[1] += v1; csum[2] += v2; csum[3] += v3;
    }
#pragma unroll
    for (int r = 0; r < 8; ++r) red1[ty * 8 + r][tx] = rsum[r];
#pragma unroll
    for (int c = 0; c < 4; ++c) red2[tx * 4 + c][ty] = csum[c];
    __syncthreads();

    if (job == 0) {
        if (t < 128) {
            float s = 0;
#pragma unroll
            for (int x = 0; x < 16; ++x) s += red1[t][x];
            m1p[((size_t)b * 2 + h) * S_ + t] = s;
        }
        if (t < 64) {
            float s = 0;
#pragma unroll
            for (int x = 0; x < 16; ++x) s += red2[t][x];
            m2[(size_t)b * S_ + h * 64 + t] = s;
        }
    } else {
        if (t < 64) {
            float s = 0;
#pragma unroll
            for (int x = 0; x < 16; ++x) s += red2[t][x];
            m3[(size_t)b * S_ + h * 64 + t] = s;
        }
    }
}

// ---------------- Kernel 3: normalize + output ----------------
// grid: B blocks, 128 threads. out[b][0:32]=m1@V/Z, [32:64]=m2@V/Z, [64:96]=m3@V/Z
__global__ void k_out(const float* __restrict__ m1p, const float* __restrict__ m2,
                      const float* __restrict__ m3, const float* __restrict__ V,
                      float* __restrict__ out) {
    int b = blockIdx.x;
    int t = threadIdx.x;
    __shared__ float ms[3][S_];
    __shared__ float zred[S_];

    float m1v = m1p[((size_t)b * 2 + 0) * S_ + t] + m1p[((size_t)b * 2 + 1) * S_ + t];
    ms[0][t] = m1v;
    ms[1][t] = m2[(size_t)b * S_ + t];
    ms[2][t] = m3[(size_t)b * S_ + t];
    zred[t] = m1v;
    __syncthreads();
    for (int off = 64; off > 0; off >>= 1) {
        if (t < off) zred[t] += zred[t + off];
        __syncthreads();
    }
    float invZ = 1.0f / zred[0];
    if (t < 96) {
        int which = t >> 5, f = t & 31;
        const float* ml = ms[which];
        const float* Vb = V + (size_t)b * S_ * F_;
        float s = 0;
        for (int s0 = 0; s0 < S_; ++s0) s += ml[s0] * Vb[s0 * F_ + f];
        out[(size_t)b * 96 + t] = s * invZ;
    }
}

extern "C" void kernel_launch(void* const* d_in, const int* in_sizes, int n_in,
                              void* d_out, int out_size, void* d_ws, size_t ws_size,
                              hipStream_t stream) {
    const float* X  = (const float*)d_in[0];
    const float* V  = (const float*)d_in[1];
    const float* W1 = (const float*)d_in[2];
    const float* b1 = (const float*)d_in[3];
    const float* W2 = (const float*)d_in[4];
    const float* b2 = (const float*)d_in[5];
    const float* W3 = (const float*)d_in[6];
    const float* b3 = (const float*)d_in[7];
    float* out = (float*)d_out;

    float* E   = (float*)d_ws;                       // [B][3][S][S]
    float* m1p = E + (size_t)B_ * 3 * S_ * S_;       // [B][2][S]
    float* m2  = m1p + (size_t)B_ * 2 * S_;          // [B][S]
    float* m3  = m2 + (size_t)B_ * S_;               // [B][S]

    k_qe<<<B_ * 3, 256, 0, stream>>>(X, W1, b1, W2, b2, W3, b3, E);
    k_gemm<<<B_ * 4, 256, 0, stream>>>(E, m1p, m2, m3);
    k_out<<<B_, 128, 0, stream>>>(m1p, m2, m3, V, out);
}

// Round 2
// 33.874 us; speedup vs baseline: 1.5280x; 1.5280x over previous
//
#include <hip/hip_runtime.h>
#include <hip/hip_bf16.h>

// ThreeWayAttention: B=32, S=128, D=32, F=32, U=11
// p_ijk ∝ E_A[i,j]·E_B[j,k]·E_C[i,k], E_X = exp(X/9), diagonals = 0.
// m1[i] = Σ_k EC[i,k]·H[i,k],  H = EA@EB        (job 0; also m3[k] = Σ_i EC⊙H)
// m2[j] = Σ_k EB[j,k]·T3[j,k], T3 = EA^T@EC     (job 1)
// out = [m1@V, m2@V, m3@V] / Z,  Z = Σ m1

#define B_ 32
#define S_ 128
#define D_ 32
#define F_ 32
#define U_ 11

// ---------------- Kernel 1: Q projections + E tiles ----------------
// grid: B*3*4 blocks (b, m, i-tile of 32 rows), 256 threads.
__global__ __launch_bounds__(256) void k_qe(const float* __restrict__ X,
    const float* __restrict__ W1, const float* __restrict__ b1,
    const float* __restrict__ W2, const float* __restrict__ b2,
    const float* __restrict__ W3, const float* __restrict__ b3,
    float* __restrict__ E) {
    int blk = blockIdx.x;
    int b = blk / 12;
    int rest = blk - b * 12;
    int m = rest >> 2;   // 0:EA(Q1,Q2) 1:EB(Q2,Q3) 2:EC(Q1,Q3)
    int tl = rest & 3;   // 32-row tile
    __shared__ float Xs[S_][D_ + 1];
    __shared__ float QR[S_][13];
    __shared__ float QL[32][13];
    __shared__ float Ws[2][D_][U_];
    __shared__ float bsh[2][U_];
    int t = threadIdx.x;

    const float* Xb = X + (size_t)b * S_ * D_;
    for (int idx = t; idx < S_ * D_; idx += 256) Xs[idx >> 5][idx & 31] = Xb[idx];
    const float* WL = (m == 0) ? W1 : (m == 1) ? W2 : W1;
    const float* WR = (m == 0) ? W2 : (m == 1) ? W3 : W3;
    const float* bL = (m == 0) ? b1 : (m == 1) ? b2 : b1;
    const float* bR = (m == 0) ? b2 : (m == 1) ? b3 : b3;
    for (int idx = t; idx < D_ * U_; idx += 256) {
        Ws[0][idx / U_][idx % U_] = WL[idx];
        Ws[1][idx / U_][idx % U_] = WR[idx];
    }
    if (t < U_) { bsh[0][t] = bL[t]; bsh[1][t] = bR[t]; }
    __syncthreads();

    if (t < 160) {
        int isR = (t < 128);
        int side = isR ? 1 : 0;
        int row = isR ? t : (tl * 32 + (t - 128));
        float q[U_];
#pragma unroll
        for (int u = 0; u < U_; ++u) q[u] = bsh[side][u];
#pragma unroll
        for (int d = 0; d < D_; ++d) {
            float x = Xs[row][d];
#pragma unroll
            for (int u = 0; u < U_; ++u) q[u] += x * Ws[side][d][u];
        }
        float* dst = isR ? &QR[t][0] : &QL[t - 128][0];
#pragma unroll
        for (int u = 0; u < U_; ++u) dst[u] = q[u];
    }
    __syncthreads();

    float* Eb = E + (size_t)(b * 3 + m) * (S_ * S_);
    const float inv9 = 1.0f / 9.0f;
    for (int idx = t; idx < 32 * S_; idx += 256) {
        int il = idx >> 7, j = idx & 127;
        int i = tl * 32 + il;
        float s = 0.f;
#pragma unroll
        for (int u = 0; u < U_; ++u) s += QL[il][u] * QR[j][u];
        Eb[i * S_ + j] = (i == j) ? 0.f : __expf(s * inv9);
    }
}

// ---------------- Kernel 2: marginals ----------------
// grid: 512 blocks = (tl 0..7)*64 + b*2 + job, 256 threads (4 waves).
// Each wave: 4 output rows; each lane: k-pair (k = 2*lane). Row-chunk of the
// contraction matrix staged in LDS (shared by all waves).
__device__ __forceinline__ float wave_sum(float v) {
#pragma unroll
    for (int off = 32; off; off >>= 1) v += __shfl_xor(v, off, 64);
    return v;
}

__global__ __launch_bounds__(256) void k_marg(const float* __restrict__ E,
    float* __restrict__ m1, float* __restrict__ m2, float* __restrict__ m3p) {
    int bid = blockIdx.x;
    int job = bid & 1;
    int b = (bid >> 1) & 31;
    int tl = bid >> 6;                  // 0..7, 16 rows per block
    const float* EA = E + (size_t)b * 3 * S_ * S_;
    const float* EB = EA + S_ * S_;
    const float* EC = EB + S_ * S_;
    int t = threadIdx.x;
    int lane = t & 63;
    int iw = __builtin_amdgcn_readfirstlane(t >> 6);
    int rb = tl * 16 + iw * 4;          // row base for this wave
    int k0 = lane * 2;

    __shared__ float RWs[32][S_];
    __shared__ float m3s[4][S_];

    float acc[4][2] = {};
    const float* RW = job ? EC : EB;    // contraction rows
    for (int ch = 0; ch < 4; ++ch) {
        int jbase = ch * 32;
        __syncthreads();
        for (int idx = t; idx < 32 * 32; idx += 256) {
            int row = idx >> 5, c4 = idx & 31;
            ((float4*)&RWs[row][0])[c4] =
                ((const float4*)(RW + (size_t)(jbase + row) * S_))[c4];
        }
        __syncthreads();
        if (job == 0) {
            const float* SC = EA + rb * S_;          // EA[rb+r][jj]
#pragma unroll 8
            for (int jl = 0; jl < 32; ++jl) {
                int jj = jbase + jl;
                float2 rv = *(const float2*)&RWs[jl][k0];
#pragma unroll
                for (int r = 0; r < 4; ++r) {
                    float a = SC[r * S_ + jj];
                    acc[r][0] += a * rv.x;
                    acc[r][1] += a * rv.y;
                }
            }
        } else {
            const float* SC = EA + rb;               // EA[jj][rb+r]
#pragma unroll 8
            for (int jl = 0; jl < 32; ++jl) {
                int jj = jbase + jl;
                float2 rv = *(const float2*)&RWs[jl][k0];
#pragma unroll
                for (int r = 0; r < 4; ++r) {
                    float a = SC[jj * S_ + r];
                    acc[r][0] += a * rv.x;
                    acc[r][1] += a * rv.y;
                }
            }
        }
    }

    // epilogue: weight, reduce
    const float* WT = job ? EB : EC;
    float s3x = 0.f, s3y = 0.f;
    float ws[4];
#pragma unroll
    for (int r = 0; r < 4; ++r) {
        float2 w = *(const float2*)(WT + (size_t)(rb + r) * S_ + k0);
        float v0 = w.x * acc[r][0], v1 = w.y * acc[r][1];
        ws[r] = v0 + v1;
        s3x += v0; s3y += v1;
    }
    float* MO = job ? m2 : m1;
#pragma unroll
    for (int r = 0; r < 4; ++r) {
        float v = wave_sum(ws[r]);
        if (lane == 0) MO[b * S_ + rb + r] = v;
    }
    if (job == 0) {
        m3s[iw][k0] = s3x;
        m3s[iw][k0 + 1] = s3y;
        __syncthreads();
        if (t < S_) {
            float v = m3s[0][t] + m3s[1][t] + m3s[2][t] + m3s[3][t];
            m3p[((size_t)b * 8 + tl) * S_ + t] = v;
        }
    }
}

// ---------------- Kernel 3: normalize + V matmul ----------------
__global__ __launch_bounds__(128) void k_out(const float* __restrict__ m1,
    const float* __restrict__ m2, const float* __restrict__ m3p,
    const float* __restrict__ V, float* __restrict__ out) {
    int b = blockIdx.x, t = threadIdx.x;
    __shared__ float ms[3][S_];
    __shared__ float zr[2];
    float v1 = m1[b * S_ + t];
    ms[0][t] = v1;
    ms[1][t] = m2[b * S_ + t];
    const float* mp = m3p + (size_t)b * 8 * S_;
    float v3 = 0.f;
#pragma unroll
    for (int q = 0; q < 8; ++q) v3 += mp[q * S_ + t];
    ms[2][t] = v3;
    float z = v1;
#pragma unroll
    for (int off = 32; off; off >>= 1) z += __shfl_xor(z, off, 64);
    if ((t & 63) == 0) zr[t >> 6] = z;
    __syncthreads();
    float invZ = 1.0f / (zr[0] + zr[1]);
    if (t < 96) {
        int which = t >> 5, f = t & 31;
        const float* ml = &ms[which][0];
        const float* Vb = V + (size_t)b * S_ * F_;
        float s = 0.f;
#pragma unroll 8
        for (int s0 = 0; s0 < S_; ++s0) s += ml[s0] * Vb[s0 * F_ + f];
        out[(size_t)b * 96 + t] = s * invZ;
    }
}

extern "C" void kernel_launch(void* const* d_in, const int* in_sizes, int n_in,
                              void* d_out, int out_size, void* d_ws, size_t ws_size,
                              hipStream_t stream) {
    const float* X  = (const float*)d_in[0];
    const float* V  = (const float*)d_in[1];
    const float* W1 = (const float*)d_in[2];
    const float* b1 = (const float*)d_in[3];
    const float* W2 = (const float*)d_in[4];
    const float* b2 = (const float*)d_in[5];
    const float* W3 = (const float*)d_in[6];
    const float* b3 = (const float*)d_in[7];
    float* out = (float*)d_out;

    float* E   = (float*)d_ws;                     // [B][3][S][S]
    float* m1  = E + (size_t)B_ * 3 * S_ * S_;     // [B][S]
    float* m2  = m1 + (size_t)B_ * S_;             // [B][S]
    float* m3p = m2 + (size_t)B_ * S_;             // [B][8][S]

    k_qe<<<B_ * 12, 256, 0, stream>>>(X, W1, b1, W2, b2, W3, b3, E);
    k_marg<<<B_ * 16, 256, 0, stream>>>(E, m1, m2, m3p);
    k_out<<<B_, 128, 0, stream>>>(m1, m2, m3p, V, out);
}

// Round 3
// 25.448 us; speedup vs baseline: 2.0340x; 1.3311x over previous
//
#include <hip/hip_runtime.h>
#include <hip/hip_bf16.h>

// ThreeWayAttention: B=32, S=128, D=32, F=32, U=11
// p_ijk ∝ E_A[i,j]·E_B[j,k]·E_C[i,k], E_X = exp(X/9), diagonals = 0.
// job0: C0[i,κ]=Σ_j EA[i,j]EB[j,κ]; m1[i]=Σ_κ EC⊙C0, m3[κ]=Σ_i EC⊙C0
// job1: C1[j,κ]=Σ_i EA[i,j]EC[i,κ]; m2[j]=Σ_κ EB⊙C1
// out = [m1@V, m2@V, m3@V]/Z, Z = Σ m1

#define B_ 32
#define S_ 128
#define D_ 32
#define F_ 32
#define U_ 11

// ---------------- Kernel 1: Q projections + E tiles ----------------
// grid: B*3*4 blocks (b, m, i-tile of 32 rows), 256 threads. (unchanged)
__global__ __launch_bounds__(256) void k_qe(const float* __restrict__ X,
    const float* __restrict__ W1, const float* __restrict__ b1,
    const float* __restrict__ W2, const float* __restrict__ b2,
    const float* __restrict__ W3, const float* __restrict__ b3,
    float* __restrict__ E) {
    int blk = blockIdx.x;
    int b = blk / 12;
    int rest = blk - b * 12;
    int m = rest >> 2;   // 0:EA(Q1,Q2) 1:EB(Q2,Q3) 2:EC(Q1,Q3)
    int tl = rest & 3;   // 32-row tile
    __shared__ float Xs[S_][D_ + 1];
    __shared__ float QR[S_][13];
    __shared__ float QL[32][13];
    __shared__ float Ws[2][D_][U_];
    __shared__ float bsh[2][U_];
    int t = threadIdx.x;

    const float* Xb = X + (size_t)b * S_ * D_;
    for (int idx = t; idx < S_ * D_; idx += 256) Xs[idx >> 5][idx & 31] = Xb[idx];
    const float* WL = (m == 0) ? W1 : (m == 1) ? W2 : W1;
    const float* WR = (m == 0) ? W2 : (m == 1) ? W3 : W3;
    const float* bL = (m == 0) ? b1 : (m == 1) ? b2 : b1;
    const float* bR = (m == 0) ? b2 : (m == 1) ? b3 : b3;
    for (int idx = t; idx < D_ * U_; idx += 256) {
        Ws[0][idx / U_][idx % U_] = WL[idx];
        Ws[1][idx / U_][idx % U_] = WR[idx];
    }
    if (t < U_) { bsh[0][t] = bL[t]; bsh[1][t] = bR[t]; }
    __syncthreads();

    if (t < 160) {
        int isR = (t < 128);
        int side = isR ? 1 : 0;
        int row = isR ? t : (tl * 32 + (t - 128));
        float q[U_];
#pragma unroll
        for (int u = 0; u < U_; ++u) q[u] = bsh[side][u];
#pragma unroll
        for (int d = 0; d < D_; ++d) {
            float x = Xs[row][d];
#pragma unroll
            for (int u = 0; u < U_; ++u) q[u] += x * Ws[side][d][u];
        }
        float* dst = isR ? &QR[t][0] : &QL[t - 128][0];
#pragma unroll
        for (int u = 0; u < U_; ++u) dst[u] = q[u];
    }
    __syncthreads();

    float* Eb = E + (size_t)(b * 3 + m) * (S_ * S_);
    const float inv9 = 1.0f / 9.0f;
    for (int idx = t; idx < 32 * S_; idx += 256) {
        int il = idx >> 7, j = idx & 127;
        int i = tl * 32 + il;
        float s = 0.f;
#pragma unroll
        for (int u = 0; u < U_; ++u) s += QL[il][u] * QR[j][u];
        Eb[i * S_ + j] = (i == j) ? 0.f : __expf(s * inv9);
    }
}

// ---------------- Kernel 2: marginals (LDS-blocked contraction) ----------------
// grid: 256 blocks = rt*64 + job*32 + b, 256 threads.
// Per block: output 32 rows (rt tile) × 128 κ, contraction over c=128.
// Thread (t): r0=(t>>5)*4 (4 rows), kap0=(t&31)*4 (4 κ). Per c: 2 LDS b128 + 16 FMA.
__global__ __launch_bounds__(256) void k_marg(const float* __restrict__ E,
    float* __restrict__ m1, float* __restrict__ m2, float* __restrict__ m3p) {
    int bid = blockIdx.x;
    int b = bid & 31;
    int job = (bid >> 5) & 1;
    int rt = bid >> 6;                  // 0..3
    const float* EA = E + (size_t)b * 3 * S_ * S_;
    const float* EB = EA + S_ * S_;
    const float* EC = EB + S_ * S_;
    const float* Bsrc = job ? EC : EB;  // contraction matrix [c][κ]
    const float* Wsrc = job ? EB : EC;  // epilogue weight rows

    __shared__ float At[S_][32];        // [c][r] 16 KB
    __shared__ float Bs[S_][S_];        // [c][κ] 64 KB
    __shared__ float m3s[8][S_];        // col-sum partials 4 KB

    int t = threadIdx.x;
    int l = t & 63;
    int r0 = (t >> 5) * 4;              // 0..28
    int kap0 = (t & 31) * 4;            // 0..124

    // ---- stage At ----
    if (job == 0) {
        // At[c][r] = EA[rt*32 + r][c]  (register transpose; r = idx&31 keeps
        // LDS write banks = r -> conflict-free, global reads L2-resident)
#pragma unroll
        for (int q = 0; q < 4; ++q) {
            int idx = t + q * 256;              // float4 idx 0..1023
            int r = idx & 31;
            int c4 = (idx >> 5) * 4;
            float4 v = *(const float4*)&EA[(size_t)(rt * 32 + r) * S_ + c4];
            At[c4 + 0][r] = v.x; At[c4 + 1][r] = v.y;
            At[c4 + 2][r] = v.z; At[c4 + 3][r] = v.w;
        }
    } else {
        // At[i][jl] = EA[i][rt*32 + jl]  (natural row-slices, contiguous writes)
#pragma unroll
        for (int q = 0; q < 4; ++q) {
            int idx = t + q * 256;              // float4 idx 0..1023
            int i = idx >> 3;
            int jl4 = (idx & 7) * 4;
            *(float4*)&At[i][jl4] =
                *(const float4*)&EA[(size_t)i * S_ + rt * 32 + jl4];
        }
    }
    // ---- stage Bs (full 128x128, coalesced) ----
#pragma unroll
    for (int q = 0; q < 16; ++q) {
        int idx = t + q * 256;                  // float4 idx 0..4095
        int row = idx >> 5;
        int c4 = (idx & 31) * 4;
        *(float4*)&Bs[row][c4] = *(const float4*)&Bsrc[(size_t)row * S_ + c4];
    }
    __syncthreads();

    // ---- main contraction: 4x4 register tile ----
    float acc[4][4] = {};
#pragma unroll 8
    for (int c = 0; c < S_; ++c) {
        float4 av = *(const float4*)&At[c][r0];
        float4 bv = *(const float4*)&Bs[c][kap0];
        acc[0][0] += av.x * bv.x; acc[0][1] += av.x * bv.y;
        acc[0][2] += av.x * bv.z; acc[0][3] += av.x * bv.w;
        acc[1][0] += av.y * bv.x; acc[1][1] += av.y * bv.y;
        acc[1][2] += av.y * bv.z; acc[1][3] += av.y * bv.w;
        acc[2][0] += av.z * bv.x; acc[2][1] += av.z * bv.y;
        acc[2][2] += av.z * bv.z; acc[2][3] += av.z * bv.w;
        acc[3][0] += av.w * bv.x; acc[3][1] += av.w * bv.y;
        acc[3][2] += av.w * bv.z; acc[3][3] += av.w * bv.w;
    }

    // ---- epilogue: weight, reduce ----
    float rs[4];
    float cs[4] = {0.f, 0.f, 0.f, 0.f};
#pragma unroll
    for (int i = 0; i < 4; ++i) {
        float4 wv = *(const float4*)&Wsrc[(size_t)(rt * 32 + r0 + i) * S_ + kap0];
        float v0 = wv.x * acc[i][0], v1 = wv.y * acc[i][1];
        float v2 = wv.z * acc[i][2], v3 = wv.w * acc[i][3];
        rs[i] = v0 + v1 + v2 + v3;
        cs[0] += v0; cs[1] += v1; cs[2] += v2; cs[3] += v3;
    }
    // row sums: reduce across the 32 lanes of each half-wave (κ space)
#pragma unroll
    for (int i = 0; i < 4; ++i) {
#pragma unroll
        for (int off = 1; off <= 16; off <<= 1) rs[i] += __shfl_xor(rs[i], off, 64);
    }
    float* MO = job ? m2 : m1;
    if ((l & 31) == 0) {
#pragma unroll
        for (int i = 0; i < 4; ++i) MO[b * S_ + rt * 32 + r0 + i] = rs[i];
    }
    // col sums (job0 only): partials per half-wave then LDS reduce
    if (job == 0) {
        int h = t >> 5;                        // 0..7
        float4 c4v = make_float4(cs[0], cs[1], cs[2], cs[3]);
        *(float4*)&m3s[h][kap0] = c4v;
        __syncthreads();
        if (t < S_) {
            float v = 0.f;
#pragma unroll
            for (int h2 = 0; h2 < 8; ++h2) v += m3s[h2][t];
            m3p[((size_t)b * 4 + rt) * S_ + t] = v;
        }
    }
}

// ---------------- Kernel 3: normalize + V matmul ----------------
__global__ __launch_bounds__(128) void k_out(const float* __restrict__ m1,
    const float* __restrict__ m2, const float* __restrict__ m3p,
    const float* __restrict__ V, float* __restrict__ out) {
    int b = blockIdx.x, t = threadIdx.x;
    __shared__ float ms[3][S_];
    __shared__ float zr[2];
    float v1 = m1[b * S_ + t];
    ms[0][t] = v1;
    ms[1][t] = m2[b * S_ + t];
    const float* mp = m3p + (size_t)b * 4 * S_;
    float v3 = mp[0 * S_ + t] + mp[1 * S_ + t] + mp[2 * S_ + t] + mp[3 * S_ + t];
    ms[2][t] = v3;
    float z = v1;
#pragma unroll
    for (int off = 32; off; off >>= 1) z += __shfl_xor(z, off, 64);
    if ((t & 63) == 0) zr[t >> 6] = z;
    __syncthreads();
    float invZ = 1.0f / (zr[0] + zr[1]);
    if (t < 96) {
        int which = t >> 5, f = t & 31;
        const float* ml = &ms[which][0];
        const float* Vb = V + (size_t)b * S_ * F_;
        float s = 0.f;
#pragma unroll 8
        for (int s0 = 0; s0 < S_; ++s0) s += ml[s0] * Vb[s0 * F_ + f];
        out[(size_t)b * 96 + t] = s * invZ;
    }
}

extern "C" void kernel_launch(void* const* d_in, const int* in_sizes, int n_in,
                              void* d_out, int out_size, void* d_ws, size_t ws_size,
                              hipStream_t stream) {
    const float* X  = (const float*)d_in[0];
    const float* V  = (const float*)d_in[1];
    const float* W1 = (const float*)d_in[2];
    const float* b1 = (const float*)d_in[3];
    const float* W2 = (const float*)d_in[4];
    const float* b2 = (const float*)d_in[5];
    const float* W3 = (const float*)d_in[6];
    const float* b3 = (const float*)d_in[7];
    float* out = (float*)d_out;

    float* E   = (float*)d_ws;                     // [B][3][S][S]
    float* m1  = E + (size_t)B_ * 3 * S_ * S_;     // [B][S]
    float* m2  = m1 + (size_t)B_ * S_;             // [B][S]
    float* m3p = m2 + (size_t)B_ * S_;             // [B][4][S]

    k_qe<<<B_ * 12, 256, 0, stream>>>(X, W1, b1, W2, b2, W3, b3, E);
    k_marg<<<B_ * 8, 256, 0, stream>>>(E, m1, m2, m3p);
    k_out<<<B_, 128, 0, stream>>>(m1, m2, m3p, V, out);
}

// Round 4
// 25.051 us; speedup vs baseline: 2.0662x; 1.0158x over previous
//
#include <hip/hip_runtime.h>
#include <hip/hip_bf16.h>

// ThreeWayAttention: B=32, S=128, D=32, F=32, U=11
// p_ijk ∝ E_A[i,j]·E_B[j,k]·E_C[i,k], E_X = exp(X/9), diagonals = 0.
// job0 (chunk cc over j): acc[i,κ] = Σ_j EA[i,j]EB[j,κ]; v = EC[i,κ]·acc
//      → m1 partial (row sums), m3 partial (col sums)
// job1 (chunk cc over i): acc[j,κ] = Σ_i EA[i,j]EC[i,κ]; v = EB[j,κ]·acc
//      → m2 partial (row sums)
// Unified per block: At[c][col] = exp(dot(QA[col],QC[c])/9)  (0 if col==c0+c)
//                    Bs[c][κ]   = exp(dot(QC[c],QK[κ])/9)    (0 if κ==c0+c)
//                    W[row][κ]  = exp(dot(QA[row],QK[κ])/9)  (0 if row==κ)
// job0: QA=Q1, QC=Q2-chunk, QK=Q3.  job1: QA=Q2, QC=Q1-chunk, QK=Q3.
// out = [m1@V, m2@V, m3@V]/Z, Z = Σ m1.

#define B_ 32
#define S_ 128
#define D_ 32
#define F_ 32
#define U_ 11
#define INV9 (1.0f / 9.0f)

__global__ __launch_bounds__(256) void k_fused(
    const float* __restrict__ X,
    const float* __restrict__ W1, const float* __restrict__ b1,
    const float* __restrict__ W2, const float* __restrict__ b2,
    const float* __restrict__ W3, const float* __restrict__ b3,
    float* __restrict__ m1p, float* __restrict__ m2p, float* __restrict__ m3p) {
    int bid = blockIdx.x;
    int b = bid & 31;
    int job = (bid >> 5) & 1;
    int cc = bid >> 6;            // 0..3
    int c0 = cc * 32;
    int t = threadIdx.x;

    __shared__ float QAt[U_][S_];      // [u][row]   rows operand
    __shared__ float QKt[U_][S_];      // [u][κ]     Q3
    __shared__ float QCt[U_][32];      // [u][c]     chunk operand
    __shared__ float Wt[3][U_][D_];    // W transposed [m][u][d]
    __shared__ float bsh[3][U_];
    __shared__ float At[32][132];      // [c][col]
    __shared__ float Bs[32][132];      // [c][κ]
    __shared__ float red[4][S_];

    // ---- stage W (transposed) + biases ----
    for (int idx = t; idx < 3 * U_ * D_; idx += 256) {
        int m = idx / (U_ * D_), r = idx - m * (U_ * D_);
        int u = r >> 5, d = r & 31;
        const float* Wm = (m == 0) ? W1 : (m == 1) ? W2 : W3;
        Wt[m][u][d] = Wm[d * U_ + u];
    }
    if (t < 3 * U_) {
        int m = t / U_, u = t - m * U_;
        const float* bm = (m == 0) ? b1 : (m == 1) ? b2 : b3;
        bsh[m][u] = bm[u];
    }
    // primary X row into regs (lanes 0..127 -> QA rows, 128..255 -> QK rows)
    int prow = t & 127;
    const float* Xrow = X + ((size_t)b * S_ + prow) * D_;
    float4 xv[8];
#pragma unroll
    for (int q = 0; q < 8; ++q) xv[q] = ((const float4*)Xrow)[q];
    __syncthreads();

    // ---- Q projections ----
    {
        int pmat = (t < 128) ? (job ? 1 : 0) : 2;   // wave-uniform
        float q[U_];
#pragma unroll
        for (int u = 0; u < U_; ++u) q[u] = bsh[pmat][u];
#pragma unroll
        for (int d4 = 0; d4 < 8; ++d4) {
            float4 x = xv[d4];
#pragma unroll
            for (int u = 0; u < U_; ++u) {
                float4 w = *(const float4*)&Wt[pmat][u][d4 * 4];
                q[u] += x.x * w.x + x.y * w.y + x.z * w.z + x.w * w.w;
            }
        }
        float* dst = (t < 128) ? &QAt[0][0] : &QKt[0][0];
#pragma unroll
        for (int u = 0; u < U_; ++u) dst[u * S_ + prow] = q[u];
    }
    if (t < 32) {   // chunk operand QC
        const float* Xr2 = X + ((size_t)b * S_ + c0 + t) * D_;
        float4 xv2[8];
#pragma unroll
        for (int q = 0; q < 8; ++q) xv2[q] = ((const float4*)Xr2)[q];
        int smat = job ? 0 : 1;
        float q2[U_];
#pragma unroll
        for (int u = 0; u < U_; ++u) q2[u] = bsh[smat][u];
#pragma unroll
        for (int d4 = 0; d4 < 8; ++d4) {
            float4 x = xv2[d4];
#pragma unroll
            for (int u = 0; u < U_; ++u) {
                float4 w = *(const float4*)&Wt[smat][u][d4 * 4];
                q2[u] += x.x * w.x + x.y * w.y + x.z * w.z + x.w * w.w;
            }
        }
#pragma unroll
        for (int u = 0; u < U_; ++u) QCt[u][t] = q2[u];
    }
    __syncthreads();

    // ---- build E chunks in LDS ----
    {
        int col4 = (t & 31) * 4;
        int cb = t >> 5;
#pragma unroll
        for (int qq = 0; qq < 4; ++qq) {
            int cq = cb + qq * 8;
            int gc = c0 + cq;
            float sa0 = 0, sa1 = 0, sa2 = 0, sa3 = 0;
            float sb0 = 0, sb1 = 0, sb2 = 0, sb3 = 0;
#pragma unroll
            for (int u = 0; u < U_; ++u) {
                float cv = QCt[u][cq];
                float4 a = *(const float4*)&QAt[u][col4];
                float4 k = *(const float4*)&QKt[u][col4];
                sa0 += a.x * cv; sa1 += a.y * cv; sa2 += a.z * cv; sa3 += a.w * cv;
                sb0 += k.x * cv; sb1 += k.y * cv; sb2 += k.z * cv; sb3 += k.w * cv;
            }
            float4 ra, rb;
            ra.x = (col4 + 0 == gc) ? 0.f : __expf(sa0 * INV9);
            ra.y = (col4 + 1 == gc) ? 0.f : __expf(sa1 * INV9);
            ra.z = (col4 + 2 == gc) ? 0.f : __expf(sa2 * INV9);
            ra.w = (col4 + 3 == gc) ? 0.f : __expf(sa3 * INV9);
            rb.x = (col4 + 0 == gc) ? 0.f : __expf(sb0 * INV9);
            rb.y = (col4 + 1 == gc) ? 0.f : __expf(sb1 * INV9);
            rb.z = (col4 + 2 == gc) ? 0.f : __expf(sb2 * INV9);
            rb.w = (col4 + 3 == gc) ? 0.f : __expf(sb3 * INV9);
            *(float4*)&At[cq][col4] = ra;
            *(float4*)&Bs[cq][col4] = rb;
        }
    }
    __syncthreads();

    // ---- main contraction: 8x8 register tile ----
    int r0 = (t >> 4) * 8;
    int k0 = (t & 15) * 8;
    float acc[8][8] = {};
#pragma unroll 4
    for (int c = 0; c < 32; ++c) {
        float4 a0 = *(const float4*)&At[c][r0];
        float4 a1 = *(const float4*)&At[c][r0 + 4];
        float4 b0v = *(const float4*)&Bs[c][k0];
        float4 b1v = *(const float4*)&Bs[c][k0 + 4];
        float av[8] = {a0.x, a0.y, a0.z, a0.w, a1.x, a1.y, a1.z, a1.w};
        float bv[8] = {b0v.x, b0v.y, b0v.z, b0v.w, b1v.x, b1v.y, b1v.z, b1v.w};
#pragma unroll
        for (int x = 0; x < 8; ++x)
#pragma unroll
            for (int y = 0; y < 8; ++y) acc[x][y] += av[x] * bv[y];
    }

    // ---- weight scores via rank-11 mini-GEMM ----
    float s3[8][8] = {};
#pragma unroll
    for (int u = 0; u < U_; ++u) {
        float4 a0 = *(const float4*)&QAt[u][r0];
        float4 a1 = *(const float4*)&QAt[u][r0 + 4];
        float4 b0v = *(const float4*)&QKt[u][k0];
        float4 b1v = *(const float4*)&QKt[u][k0 + 4];
        float av[8] = {a0.x, a0.y, a0.z, a0.w, a1.x, a1.y, a1.z, a1.w};
        float bv[8] = {b0v.x, b0v.y, b0v.z, b0v.w, b1v.x, b1v.y, b1v.z, b1v.w};
#pragma unroll
        for (int x = 0; x < 8; ++x)
#pragma unroll
            for (int y = 0; y < 8; ++y) s3[x][y] += av[x] * bv[y];
    }

    // ---- combine: w = exp(s3/9) (0 on diag), v = w*acc, row/col sums ----
    float rs[8] = {}, cs[8] = {};
#pragma unroll
    for (int x = 0; x < 8; ++x) {
#pragma unroll
        for (int y = 0; y < 8; ++y) {
            float w = ((r0 + x) == (k0 + y)) ? 0.f : __expf(s3[x][y] * INV9);
            float v = w * acc[x][y];
            rs[x] += v; cs[y] += v;
        }
    }

    // row sums -> m1 (job0) / m2 (job1): reduce over the 16 κ-lanes
#pragma unroll
    for (int x = 0; x < 8; ++x) {
        rs[x] += __shfl_xor(rs[x], 1);
        rs[x] += __shfl_xor(rs[x], 2);
        rs[x] += __shfl_xor(rs[x], 4);
        rs[x] += __shfl_xor(rs[x], 8);
    }
    if ((t & 15) == 0) {
        float* MO = job ? m2p : m1p;
#pragma unroll
        for (int x = 0; x < 8; ++x) MO[((size_t)b * 4 + cc) * S_ + r0 + x] = rs[x];
    }
    // col sums -> m3 (job0 only): reduce over row-groups, then across waves
    if (!job) {
#pragma unroll
        for (int y = 0; y < 8; ++y) {
            cs[y] += __shfl_xor(cs[y], 16);
            cs[y] += __shfl_xor(cs[y], 32);
        }
        int wv = t >> 6;
        if (((t >> 4) & 3) == 0) {
            *(float4*)&red[wv][k0] = make_float4(cs[0], cs[1], cs[2], cs[3]);
            *(float4*)&red[wv][k0 + 4] = make_float4(cs[4], cs[5], cs[6], cs[7]);
        }
        __syncthreads();
        if (t < S_)
            m3p[((size_t)b * 4 + cc) * S_ + t] =
                red[0][t] + red[1][t] + red[2][t] + red[3][t];
    }
}

// ---------------- Kernel 2: gather partials, normalize, V matmul ----------------
__global__ __launch_bounds__(128) void k_out(const float* __restrict__ m1p,
    const float* __restrict__ m2p, const float* __restrict__ m3p,
    const float* __restrict__ V, float* __restrict__ out) {
    int b = blockIdx.x, t = threadIdx.x;
    __shared__ float ms[3][S_];
    __shared__ float Vs[S_][33];
    __shared__ float zr[2];
    const float* Vb = V + (size_t)b * S_ * F_;
#pragma unroll
    for (int q = 0; q < 8; ++q) {
        int idx = t + q * 128;            // float4 idx 0..1023
        int row = idx >> 3, c4 = (idx & 7) * 4;
        float4 v = *(const float4*)&Vb[row * F_ + c4];
        Vs[row][c4 + 0] = v.x; Vs[row][c4 + 1] = v.y;
        Vs[row][c4 + 2] = v.z; Vs[row][c4 + 3] = v.w;
    }
    size_t base = (size_t)b * 4 * S_ + t;
    float v1 = m1p[base] + m1p[base + S_] + m1p[base + 2 * S_] + m1p[base + 3 * S_];
    ms[0][t] = v1;
    ms[1][t] = m2p[base] + m2p[base + S_] + m2p[base + 2 * S_] + m2p[base + 3 * S_];
    ms[2][t] = m3p[base] + m3p[base + S_] + m3p[base + 2 * S_] + m3p[base + 3 * S_];
    float z = v1;
#pragma unroll
    for (int off = 32; off; off >>= 1) z += __shfl_xor(z, off);
    if ((t & 63) == 0) zr[t >> 6] = z;
    __syncthreads();
    float invZ = 1.0f / (zr[0] + zr[1]);
    if (t < 96) {
        int which = t >> 5, f = t & 31;
        const float* ml = &ms[which][0];
        float s = 0.f;
#pragma unroll 8
        for (int s0 = 0; s0 < S_; ++s0) s += ml[s0] * Vs[s0][f];
        out[(size_t)b * 96 + t] = s * invZ;
    }
}

extern "C" void kernel_launch(void* const* d_in, const int* in_sizes, int n_in,
                              void* d_out, int out_size, void* d_ws, size_t ws_size,
                              hipStream_t stream) {
    const float* X  = (const float*)d_in[0];
    const float* V  = (const float*)d_in[1];
    const float* W1 = (const float*)d_in[2];
    const float* b1 = (const float*)d_in[3];
    const float* W2 = (const float*)d_in[4];
    const float* b2 = (const float*)d_in[5];
    const float* W3 = (const float*)d_in[6];
    const float* b3 = (const float*)d_in[7];
    float* out = (float*)d_out;

    float* m1p = (float*)d_ws;                     // [B][4][S]
    float* m2p = m1p + (size_t)B_ * 4 * S_;        // [B][4][S]
    float* m3p = m2p + (size_t)B_ * 4 * S_;        // [B][4][S]

    k_fused<<<256, 256, 0, stream>>>(X, W1, b1, W2, b2, W3, b3, m1p, m2p, m3p);
    k_out<<<B_, 128, 0, stream>>>(m1p, m2p, m3p, V, out);
}